// Round 4
// baseline (260.020 us; speedup 1.0000x reference)
//
#include <hip/hip_runtime.h>

// GetWeightMatrix: weight = 1 + 1.5 * sum_{5x5 shifts}(y_pad != argmax_c(x))
// x: [8, 21, 512, 512] f32, y: [8, 512, 512] i32, out: [8, 1, 512, 512] f32
// HBM-bound on x (176 MB of ~193 MB total). One thread = 8 h-pixels (2 float4
// per channel, doubled MEM ILP). x loads nontemporal (pure streaming, no
// reuse) to keep L2 for y (5x reuse) and the store stream.
// R3 fix: __builtin_nontemporal_load needs a native clang vector type, not
// HIP_vector_type — use ext_vector_type(4) float.

constexpr int B = 8;
constexpr int C = 21;
constexpr int W = 512;
constexpr int H = 512;
constexpr int PIX = W * H;

typedef float f32x4 __attribute__((ext_vector_type(4)));

__global__ __launch_bounds__(256) void getweight_kernel(
    const float* __restrict__ x, const int* __restrict__ y,
    float* __restrict__ out)
{
    const int tid = blockIdx.x * blockDim.x + threadIdx.x;
    const int gpr = H / 8;        // 64 8-pixel groups per row
    const int gpi = W * gpr;      // 32768 groups per image
    const int b   = tid / gpi;
    const int rem = tid - b * gpi;
    const int w   = rem / gpr;
    const int h   = (rem - w * gpr) << 3;   // base h of this thread's 8 pixels

    // ---- argmax over 21 channels, 8 pixels at once (2x float4 per channel) ----
    const float* xp = x + (size_t)b * C * PIX + (size_t)w * H + h;
    f32x4 bestA = __builtin_nontemporal_load(reinterpret_cast<const f32x4*>(xp));
    f32x4 bestB = __builtin_nontemporal_load(reinterpret_cast<const f32x4*>(xp + 4));
    int am[8] = {0, 0, 0, 0, 0, 0, 0, 0};
#pragma unroll
    for (int c = 1; c < C; ++c) {
        const float* xc = xp + (size_t)c * PIX;
        f32x4 vA = __builtin_nontemporal_load(reinterpret_cast<const f32x4*>(xc));
        f32x4 vB = __builtin_nontemporal_load(reinterpret_cast<const f32x4*>(xc + 4));
        // strict > keeps the FIRST max index, matching jnp.argmax tie-break
#pragma unroll
        for (int j = 0; j < 4; ++j) {
            if (vA[j] > bestA[j]) { bestA[j] = vA[j]; am[j] = c; }
            if (vB[j] > bestB[j]) { bestB[j] = vB[j]; am[4 + j] = c; }
        }
    }

    // ---- 5x5 neighborhood mismatch count vs y (zero-pad => OOB label 0) ----
    // Needed columns per row: h-2 .. h+9 == elements 2..13 of the aligned
    // 16-int span starting at h-4. Four int4 loads, edge-predicated to 0.
    const int* yb = y + b * PIX;
    int cnt[8] = {0, 0, 0, 0, 0, 0, 0, 0};
    const int4 zero4 = make_int4(0, 0, 0, 0);
#pragma unroll
    for (int di = 0; di < 5; ++di) {
        const int ww = w + di - 2;
        const bool wok = (unsigned)ww < (unsigned)W;
        const int* row = yb + ww * H;
        // h is a multiple of 8: va needs h-4 >= 0 (h>0); vd needs h+12 <= H (h+8<H)
        const int4 va = (wok && h > 0)     ? *reinterpret_cast<const int4*>(row + h - 4) : zero4;
        const int4 vb = (wok)              ? *reinterpret_cast<const int4*>(row + h)     : zero4;
        const int4 vc = (wok)              ? *reinterpret_cast<const int4*>(row + h + 4) : zero4;
        const int4 vd = (wok && h + 8 < H) ? *reinterpret_cast<const int4*>(row + h + 8) : zero4;
        const int yr[12] = {va.z, va.w, vb.x, vb.y, vb.z, vb.w,
                            vc.x, vc.y, vc.z, vc.w, vd.x, vd.y};
#pragma unroll
        for (int j = 0; j < 8; ++j) {
#pragma unroll
            for (int dj = 0; dj < 5; ++dj) {
                cnt[j] += (yr[j + dj] != am[j]) ? 1 : 0;
            }
        }
    }

    float* op = out + (size_t)b * PIX + (size_t)w * H + h;
    float4 r0, r1;
    r0.x = 1.0f + 1.5f * (float)cnt[0];
    r0.y = 1.0f + 1.5f * (float)cnt[1];
    r0.z = 1.0f + 1.5f * (float)cnt[2];
    r0.w = 1.0f + 1.5f * (float)cnt[3];
    r1.x = 1.0f + 1.5f * (float)cnt[4];
    r1.y = 1.0f + 1.5f * (float)cnt[5];
    r1.z = 1.0f + 1.5f * (float)cnt[6];
    r1.w = 1.0f + 1.5f * (float)cnt[7];
    *reinterpret_cast<float4*>(op)     = r0;
    *reinterpret_cast<float4*>(op + 4) = r1;
}

extern "C" void kernel_launch(void* const* d_in, const int* in_sizes, int n_in,
                              void* d_out, int out_size, void* d_ws, size_t ws_size,
                              hipStream_t stream) {
    const float* x = (const float*)d_in[0];   // [8,21,512,512] f32
    const int*   y = (const int*)d_in[1];     // [8,512,512] i32
    float* out = (float*)d_out;               // [8,1,512,512] f32

    const int total_threads = B * PIX / 8;    // 262144
    const int block = 256;
    const int grid = total_threads / block;   // 1024
    getweight_kernel<<<grid, block, 0, stream>>>(x, y, out);
}

// Round 5
// 249.576 us; speedup vs baseline: 1.0418x; 1.0418x over previous
//
#include <hip/hip_runtime.h>

// GetWeightMatrix: weight = 1 + 1.5 * sum_{5x5 shifts}(y_pad != argmax_c(x))
// x: [8, 21, 512, 512] f32, y: [8, 512, 512] i32, out: [8, 1, 512, 512] f32
// HBM-bound on x (176 MB of ~193 MB total traffic; floor ~31 us at 6.3 TB/s).
// Best variant (R1-measured 248.6 us total incl. ~209 us harness fills):
// one thread = 4 h-pixels, float4 x loads, 8192 waves (32/CU) for latency
// hiding, plain cached loads (nt regressed: R4), scalar predicated y loads
// (int4 y was neutral: R2).

constexpr int B = 8;
constexpr int C = 21;
constexpr int W = 512;
constexpr int H = 512;
constexpr int PIX = W * H;

__global__ __launch_bounds__(256) void getweight_kernel(
    const float* __restrict__ x, const int* __restrict__ y,
    float* __restrict__ out)
{
    const int tid = blockIdx.x * blockDim.x + threadIdx.x;
    const int gpr = H / 4;        // 128 float4-groups per row
    const int gpi = W * gpr;      // 65536 groups per image
    const int b   = tid / gpi;
    const int rem = tid - b * gpi;
    const int w   = rem / gpr;
    const int h   = (rem - w * gpr) << 2;   // base h of this thread's 4 pixels

    // ---- argmax over 21 channels, 4 pixels at once (float4 strided loads) ----
    const float* xp = x + (size_t)b * C * PIX + (size_t)w * H + h;
    float4 best = *reinterpret_cast<const float4*>(xp);
    int am0 = 0, am1 = 0, am2 = 0, am3 = 0;
#pragma unroll
    for (int c = 1; c < C; ++c) {
        float4 v = *reinterpret_cast<const float4*>(xp + (size_t)c * PIX);
        // strict > keeps the FIRST max index, matching jnp.argmax tie-break
        if (v.x > best.x) { best.x = v.x; am0 = c; }
        if (v.y > best.y) { best.y = v.y; am1 = c; }
        if (v.z > best.z) { best.z = v.z; am2 = c; }
        if (v.w > best.w) { best.w = v.w; am3 = c; }
    }
    const int xm[4] = {am0, am1, am2, am3};

    // ---- 5x5 neighborhood mismatch count vs y (zero-pad => OOB label 0) ----
    const int* yb = y + b * PIX;
    int cnt[4] = {0, 0, 0, 0};
#pragma unroll
    for (int di = 0; di < 5; ++di) {
        const int ww = w + di - 2;
        const bool wok = (unsigned)ww < (unsigned)W;
        int yr[8];  // y row values covering h-2 .. h+5 (all 4 pixels x 5 dj)
#pragma unroll
        for (int k = 0; k < 8; ++k) {
            const int hh = h + k - 2;
            const bool ok = wok && ((unsigned)hh < (unsigned)H);
            yr[k] = ok ? yb[ww * H + hh] : 0;   // pad value = class 0
        }
#pragma unroll
        for (int j = 0; j < 4; ++j) {
#pragma unroll
            for (int dj = 0; dj < 5; ++dj) {
                cnt[j] += (yr[j + dj] != xm[j]) ? 1 : 0;
            }
        }
    }

    float4 res;
    res.x = 1.0f + 1.5f * (float)cnt[0];
    res.y = 1.0f + 1.5f * (float)cnt[1];
    res.z = 1.0f + 1.5f * (float)cnt[2];
    res.w = 1.0f + 1.5f * (float)cnt[3];
    *reinterpret_cast<float4*>(out + (size_t)b * PIX + (size_t)w * H + h) = res;
}

extern "C" void kernel_launch(void* const* d_in, const int* in_sizes, int n_in,
                              void* d_out, int out_size, void* d_ws, size_t ws_size,
                              hipStream_t stream) {
    const float* x = (const float*)d_in[0];   // [8,21,512,512] f32
    const int*   y = (const int*)d_in[1];     // [8,512,512] i32
    float* out = (float*)d_out;               // [8,1,512,512] f32

    const int total_threads = B * PIX / 4;    // 524288
    const int block = 256;
    const int grid = total_threads / block;   // 2048
    getweight_kernel<<<grid, block, 0, stream>>>(x, y, out);
}